// Round 1
// baseline (557.857 us; speedup 1.0000x reference)
//
#include <hip/hip_runtime.h>

// receptive_attention: out[b,h,i,j] = (|i-j| <= 128) ? dot(q[b,h,i,:], k[b,h,j,:]) : 0
// B=2 H=16 L=2048 D=64, fp32 in/out.
//
// Roofline: output is 537 MB that MUST be fully written (harness poisons d_out).
// Band fraction ~12.5% -> compute is small (~2.7 GFLOP fp32); kernel is a
// write-bandwidth problem. One 64x64 tile per 256-thread block:
//   |ti-tj| > 2  -> pure float4 zero store (87% of blocks)
//   |ti-tj| <= 2 -> LDS-tiled fp32 dot, 4x4 micro-tile/thread, masked store.

constexpr int L = 2048;
constexpr int D = 64;
constexpr int R = 128;
constexpr int TILE = 64;
constexpr int BH = 32;              // B*H
constexpr int LDS_STRIDE = D + 1;   // 65: Q-tile reads hit 4 distinct banks,
                                    // K-tile reads 2-way (free per m136)

__global__ __launch_bounds__(256)
void receptive_attention_kernel(const float* __restrict__ q,
                                const float* __restrict__ k,
                                float* __restrict__ out) {
    const int tj = blockIdx.x;
    const int ti = blockIdx.y;
    const int bh = blockIdx.z;
    const int t  = threadIdx.x;

    float* outTile = out + (size_t)bh * L * L + (size_t)(ti * TILE) * L + tj * TILE;

    int dt = ti - tj; if (dt < 0) dt = -dt;

    if (dt > 2) {
        // Fully outside the band: stream zeros. 64x64 floats = 1024 float4,
        // 256 threads x 4 stores, coalesced.
        const float4 z = make_float4(0.f, 0.f, 0.f, 0.f);
        #pragma unroll
        for (int it = 0; it < 4; ++it) {
            int idx  = t + it * 256;     // float4 index within tile
            int row  = idx >> 4;         // 16 float4 per 64-col row
            int col  = (idx & 15) * 4;
            *reinterpret_cast<float4*>(outTile + (size_t)row * L + col) = z;
        }
        return;
    }

    // ---- band tile: compute Q_tile @ K_tile^T ----
    __shared__ float Qs[TILE * LDS_STRIDE];
    __shared__ float Ks[TILE * LDS_STRIDE];

    const float* qTile = q + (size_t)bh * L * D + (size_t)(ti * TILE) * D;
    const float* kTile = k + (size_t)bh * L * D + (size_t)(tj * TILE) * D;

    // Stage both tiles: 64 rows x 64 d = 1024 float4 each; 4 per thread, coalesced.
    #pragma unroll
    for (int it = 0; it < 4; ++it) {
        int idx = t + it * 256;          // float4 index
        int row = idx >> 4;
        int col = (idx & 15) * 4;
        float4 qv = *reinterpret_cast<const float4*>(qTile + row * D + col);
        float4 kv = *reinterpret_cast<const float4*>(kTile + row * D + col);
        float* qd = &Qs[row * LDS_STRIDE + col];
        qd[0] = qv.x; qd[1] = qv.y; qd[2] = qv.z; qd[3] = qv.w;
        float* kd = &Ks[row * LDS_STRIDE + col];
        kd[0] = kv.x; kd[1] = kv.y; kd[2] = kv.z; kd[3] = kv.w;
    }
    __syncthreads();

    const int tr = (t >> 4) * 4;   // micro-tile base row (0..60)
    const int tc = (t & 15) * 4;   // micro-tile base col (0..60)

    float acc[4][4] = {};
    #pragma unroll 8
    for (int d = 0; d < D; ++d) {
        float a0 = Qs[(tr + 0) * LDS_STRIDE + d];
        float a1 = Qs[(tr + 1) * LDS_STRIDE + d];
        float a2 = Qs[(tr + 2) * LDS_STRIDE + d];
        float a3 = Qs[(tr + 3) * LDS_STRIDE + d];
        float b0 = Ks[(tc + 0) * LDS_STRIDE + d];
        float b1 = Ks[(tc + 1) * LDS_STRIDE + d];
        float b2 = Ks[(tc + 2) * LDS_STRIDE + d];
        float b3 = Ks[(tc + 3) * LDS_STRIDE + d];
        acc[0][0] += a0 * b0; acc[0][1] += a0 * b1; acc[0][2] += a0 * b2; acc[0][3] += a0 * b3;
        acc[1][0] += a1 * b0; acc[1][1] += a1 * b1; acc[1][2] += a1 * b2; acc[1][3] += a1 * b3;
        acc[2][0] += a2 * b0; acc[2][1] += a2 * b1; acc[2][2] += a2 * b2; acc[2][3] += a2 * b3;
        acc[3][0] += a3 * b0; acc[3][1] += a3 * b1; acc[3][2] += a3 * b2; acc[3][3] += a3 * b3;
    }

    // Masked store: 4 rows x float4 per thread, band check per element.
    const int gi0 = ti * TILE + tr;
    const int gj0 = tj * TILE + tc;
    #pragma unroll
    for (int r = 0; r < 4; ++r) {
        int gi = gi0 + r;
        float4 v;
        float* vp = &v.x;
        #pragma unroll
        for (int c = 0; c < 4; ++c) {
            int gj = gj0 + c;
            int diff = gi - gj;
            if (diff < 0) diff = -diff;
            vp[c] = (diff <= R) ? acc[r][c] : 0.f;
        }
        *reinterpret_cast<float4*>(outTile + (size_t)(tr + r) * L + tc) = v;
    }
}

extern "C" void kernel_launch(void* const* d_in, const int* in_sizes, int n_in,
                              void* d_out, int out_size, void* d_ws, size_t ws_size,
                              hipStream_t stream) {
    const float* q = (const float*)d_in[0];
    const float* k = (const float*)d_in[1];
    float* out = (float*)d_out;

    dim3 grid(L / TILE, L / TILE, BH);   // (32, 32, 32)
    receptive_attention_kernel<<<grid, 256, 0, stream>>>(q, k, out);
}